// Round 1
// baseline (471.536 us; speedup 1.0000x reference)
//
#include <hip/hip_runtime.h>
#include <stdint.h>

// ---------------------------------------------------------------------------
// NeuralEmbeddingLayer: patchify -> GEMM1(+bias,gelu,x32) -> GEMM2(+bias,+pos)
// R3: 256x256 8-phase pipelined GEMM (T2+T3+T4+T5):
//  - 8 waves (2Mx4N), per-wave 128x64 output, acc[8][4]
//  - LDS 128 KiB: 2 double-buffered K-tiles (A 32KB + B 32KB each), BK=64
//  - per K-tile 4 phases: {stage 16KB chunk of tile t+1 | counted vmcnt |
//    barrier | ds_read subtile | setprio(1) 16 MFMA setprio(0)}
//  - chunk issue order c1(A-lo),c2(B-lo),c3(B-hi),c4(A-hi); consumption
//    deadlines q1,q1,q2,q3 => steady-state s_waitcnt vmcnt(6) (3 chunks in
//    flight, never drained to 0 in the main loop). Tail tile drains 4->2->0.
//  - XOR swizzle slot = chunk ^ (row&7) with pre-swizzled global source
//    (identical data-path formulas to the verified 128x128 kernel).
//  - bijective XCD swizzle (m204), row-major within XCD chunk.
// ---------------------------------------------------------------------------

typedef __attribute__((ext_vector_type(8))) short bf16x8;   // 8 bf16 = 4 VGPRs
typedef __attribute__((ext_vector_type(4))) float f32x4;    // MFMA C/D frag

#define VMCNT(n) asm volatile("s_waitcnt vmcnt(" #n ")" ::: "memory")
#define CFENCE() asm volatile("" ::: "memory")

__device__ __forceinline__ unsigned short f2bf(float f) {
  union { float f; unsigned u; } v; v.f = f;
  const unsigned u = v.u;
  return (unsigned short)((u + 0x7fffu + ((u >> 16) & 1u)) >> 16);  // RNE
}

__device__ __forceinline__ float gelu_exact(float x) {
  return 0.5f * x * (1.0f + erff(x * 0.70710678118654752440f));
}

// async global->LDS, 16B per lane. Dest granules are lane-linear; source is
// per-lane (pre-swizzled).
__device__ __forceinline__ void gl_lds16(const unsigned short* g, unsigned short* l) {
  __builtin_amdgcn_global_load_lds(
      (const __attribute__((address_space(1))) unsigned int*)g,
      (__attribute__((address_space(3))) unsigned int*)l, 16, 0, 0);
}

// --------------------------- prep kernels ----------------------------------

__global__ void cast_f32_bf16(const float* __restrict__ src,
                              unsigned short* __restrict__ dst, int n) {
  const int i = blockIdx.x * 256 + threadIdx.x;
  if (i < n) dst[i] = f2bf(src[i]);
}

// spikes [32][512][1024] f32 -> patches bf16 [32768][512]
__global__ void patchify(const float* __restrict__ spikes,
                         unsigned short* __restrict__ P) {
  const int idx = blockIdx.x * 256 + threadIdx.x;
  const int m = idx >> 7;
  const int c = (idx & 127) << 2;
  const int b = m >> 10, p = m & 1023;
  const int pt = p >> 5, ps = p & 31;
  const int ft = c >> 5, fs = c & 31;
  const float4 v = *(const float4*)(spikes +
      (size_t)(((b << 9) + pt * 16 + ft) << 10) + ps * 32 + fs);
  ushort4 o;
  o.x = f2bf(v.x); o.y = f2bf(v.y); o.z = f2bf(v.z); o.w = f2bf(v.w);
  *(ushort4*)(P + (size_t)m * 512 + c) = o;
}

// G rows b*1025 = gelu(cls)*32 (cls skips b_embed); zero pad rows [32800,32896)
__global__ void g0_and_pad(const float* __restrict__ cls,
                           unsigned short* __restrict__ G) {
  const int i = blockIdx.x * 256 + threadIdx.x;  // 98304 threads
  G[(size_t)32800 * 1024 + i] = 0;
  if (i < 1024) {
    const unsigned short bv = f2bf(gelu_exact(cls[i]) * 32.0f);
    for (int b = 0; b < 32; ++b) G[(size_t)(b * 1025) * 1024 + i] = bv;
  }
}

__global__ void mask_stamp(float* __restrict__ out) {
  const int i = blockIdx.x * 256 + threadIdx.x;
  if (i < 32800) {
    out[33587200 + i] = 1.0f;
    out[33587200 + 32800 + i] = (float)(i % 1025);
  }
}

// --------------------------- staging helpers -------------------------------
// LDS region per matrix per buffer: 256 rows x 64 bf16 (granule (r,slot),
// slot 0..7, 16B each). Granule (r,slot) holds global k-chunk slot^(r&7).
// A chunks: hi=0  -> rows {0..63, 128..191}   (granules [0,512)+[1024,1536))
//           hi=512-> rows {64..127, 192..255}
// B chunks: hi=0  -> rows {0-31,64-95,128-159,192-223}
//           hi=256-> rows {32-63,96-127,160-191,224-255}
// Each chunk = 16 KB = 2 gl_lds per thread (m0 = wave*2).

__device__ __forceinline__ void stageA_chunk(const unsigned short* __restrict__ A,
    int K, int rowStart, int rmax, unsigned short* lds, int k0, int m0, int lane,
    int hi) {
#pragma unroll
  for (int l = 0; l < 2; ++l) {
    const int m = m0 + l;
    const int g = ((m & 8) ? (1024 + ((m & 7) << 6)) : (m << 6)) + hi + lane;
    const int r = g >> 3, slot = g & 7;
    const int kc = (slot ^ (r & 7)) << 3;
    int rg = rowStart + r;
    if (rg > rmax) rg = rmax;   // last GEMM2 row-block: clamp into zeroed rows
    gl_lds16(A + (size_t)rg * K + (k0 + kc), lds + g * 8);
  }
}

__device__ __forceinline__ void stageB_chunk(const unsigned short* __restrict__ B,
    int K, int colStart, unsigned short* lds, int k0, int m0, int lane, int hi) {
#pragma unroll
  for (int l = 0; l < 2; ++l) {
    const int m = m0 + l;
    const int g = ((m >> 2) << 9) + ((m & 3) << 6) + hi + lane;
    const int r = g >> 3, slot = g & 7;
    const int kc = (slot ^ (r & 7)) << 3;
    gl_lds16(B + (size_t)(colStart + r) * K + (k0 + kc), lds + g * 8);
  }
}

// --------------------------- NT GEMM core ----------------------------------
// C[M,N] = A[M,K]*B[N,K]^T. 256x256 tile, BK=64, 8 waves x (8x4) 16x16x32 mfma.
template <int K, bool GELU_EPI>
__global__ __launch_bounds__(512, 2) void gemm_bt(
    const unsigned short* __restrict__ A, const unsigned short* __restrict__ B,
    const float* __restrict__ bias, unsigned short* __restrict__ Cg,
    float* __restrict__ Cf, const float* __restrict__ pos,
    int Mvalid, int rmax, int nRowBlk) {
  __shared__ __align__(16) unsigned short lsA[2][16384];
  __shared__ __align__(16) unsigned short lsB[2][16384];
  constexpr int NT = K / 64;

  const int tid = threadIdx.x;
  const int lane = tid & 63;
  const int w = tid >> 6;
  const int quad = lane >> 4;
  const int l16 = lane & 15;
  const int wm = (w >> 2) * 128;   // 2 wave-rows
  const int wn = (w & 3) * 64;     // 4 wave-cols
  const int m0 = w * 2;

  // bijective XCD swizzle (m204): nwg need not be divisible by 8.
  const int nwg = nRowBlk * 4;
  const int q = nwg >> 3, rr = nwg & 7;
  const int xcd = blockIdx.x & 7, jj = blockIdx.x >> 3;
  const int wgid =
      (xcd < rr ? xcd * (q + 1) : rr * (q + 1) + (xcd - rr) * q) + jj;
  const int rowStart = (wgid >> 2) << 8;   // row-major: 4 col-blocks share A
  const int colStart = (wgid & 3) << 8;

  f32x4 acc[8][4];
  const f32x4 z = {0.f, 0.f, 0.f, 0.f};
#pragma unroll
  for (int i = 0; i < 8; ++i)
#pragma unroll
    for (int j = 0; j < 4; ++j) acc[i][j] = z;

  // prologue: tile 0 -> buffer 0 (chunk order c1,c2,c3,c4)
  stageA_chunk(A, K, rowStart, rmax, lsA[0], 0, m0, lane, 0);
  stageB_chunk(B, K, colStart, lsB[0], 0, m0, lane, 0);
  stageB_chunk(B, K, colStart, lsB[0], 0, m0, lane, 256);
  stageA_chunk(A, K, rowStart, rmax, lsA[0], 0, m0, lane, 512);

  // fragment read bases (elems). slot = (k_chunk) ^ (r&7); r&7 == l16&7.
  const int aoff = (wm + l16) << 6;
  const int boff = (wn + l16) << 6;
  const int sl0 = (quad ^ (l16 & 7)) << 3;         // k-slice 0 chunk = quad
  const int sl1 = ((4 + quad) ^ (l16 & 7)) << 3;   // k-slice 1 chunk = 4+quad

  for (int t = 0; t < NT; ++t) {
    const int cur = t & 1;
    const unsigned short* cA = lsA[cur];
    const unsigned short* cB = lsB[cur];
    unsigned short* nA = lsA[cur ^ 1];
    unsigned short* nB = lsB[cur ^ 1];
    const int kn = (t + 1) << 6;
    const bool pf = (t + 1 < NT);

    bf16x8 a0[4][2], a1[4][2], b0[2][2], b1[2][2];

    // ---- q1: needs c1(A rows 0-63/128-191) + c2(B lo-stripes) ----
    if (pf) {
      stageA_chunk(A, K, rowStart, rmax, nA, kn, m0, lane, 0);   // c1 of t+1
      VMCNT(6);
    } else {
      VMCNT(4);
    }
    __builtin_amdgcn_s_barrier();
    CFENCE();
#pragma unroll
    for (int i = 0; i < 4; ++i) {
      a0[i][0] = *(const bf16x8*)(cA + aoff + i * 1024 + sl0);
      a0[i][1] = *(const bf16x8*)(cA + aoff + i * 1024 + sl1);
    }
#pragma unroll
    for (int j = 0; j < 2; ++j) {
      b0[j][0] = *(const bf16x8*)(cB + boff + j * 1024 + sl0);
      b0[j][1] = *(const bf16x8*)(cB + boff + j * 1024 + sl1);
    }
    __builtin_amdgcn_s_setprio(1);
#pragma unroll
    for (int i = 0; i < 4; ++i)
#pragma unroll
      for (int j = 0; j < 2; ++j) {
        acc[i][j] = __builtin_amdgcn_mfma_f32_16x16x32_bf16(a0[i][0], b0[j][0], acc[i][j], 0, 0, 0);
        acc[i][j] = __builtin_amdgcn_mfma_f32_16x16x32_bf16(a0[i][1], b0[j][1], acc[i][j], 0, 0, 0);
      }
    __builtin_amdgcn_s_setprio(0);

    // ---- q2: needs c3 (B hi-stripes) ----
    if (pf) {
      stageB_chunk(B, K, colStart, nB, kn, m0, lane, 0);         // c2 of t+1
      VMCNT(6);
    } else {
      VMCNT(2);
    }
    __builtin_amdgcn_s_barrier();
    CFENCE();
#pragma unroll
    for (int j = 0; j < 2; ++j) {
      b1[j][0] = *(const bf16x8*)(cB + boff + (j + 2) * 1024 + sl0);
      b1[j][1] = *(const bf16x8*)(cB + boff + (j + 2) * 1024 + sl1);
    }
    __builtin_amdgcn_s_setprio(1);
#pragma unroll
    for (int i = 0; i < 4; ++i)
#pragma unroll
      for (int j = 0; j < 2; ++j) {
        acc[i][j + 2] = __builtin_amdgcn_mfma_f32_16x16x32_bf16(a0[i][0], b1[j][0], acc[i][j + 2], 0, 0, 0);
        acc[i][j + 2] = __builtin_amdgcn_mfma_f32_16x16x32_bf16(a0[i][1], b1[j][1], acc[i][j + 2], 0, 0, 0);
      }
    __builtin_amdgcn_s_setprio(0);

    // ---- q3: needs c4 (A rows 64-127/192-255) ----
    if (pf) {
      stageB_chunk(B, K, colStart, nB, kn, m0, lane, 256);       // c3 of t+1
      VMCNT(6);
    } else {
      VMCNT(0);
    }
    __builtin_amdgcn_s_barrier();
    CFENCE();
#pragma unroll
    for (int i = 0; i < 4; ++i) {
      a1[i][0] = *(const bf16x8*)(cA + aoff + (i + 4) * 1024 + sl0);
      a1[i][1] = *(const bf16x8*)(cA + aoff + (i + 4) * 1024 + sl1);
    }
    __builtin_amdgcn_s_setprio(1);
#pragma unroll
    for (int i = 0; i < 4; ++i)
#pragma unroll
      for (int j = 0; j < 2; ++j) {
        acc[i + 4][j] = __builtin_amdgcn_mfma_f32_16x16x32_bf16(a1[i][0], b0[j][0], acc[i + 4][j], 0, 0, 0);
        acc[i + 4][j] = __builtin_amdgcn_mfma_f32_16x16x32_bf16(a1[i][1], b0[j][1], acc[i + 4][j], 0, 0, 0);
      }
    __builtin_amdgcn_s_setprio(0);

    // ---- q4: pure MFMA (regs already live) ----
    if (pf) stageA_chunk(A, K, rowStart, rmax, nA, kn, m0, lane, 512);  // c4
    __builtin_amdgcn_s_setprio(1);
#pragma unroll
    for (int i = 0; i < 4; ++i)
#pragma unroll
      for (int j = 0; j < 2; ++j) {
        acc[i + 4][j + 2] = __builtin_amdgcn_mfma_f32_16x16x32_bf16(a1[i][0], b1[j][0], acc[i + 4][j + 2], 0, 0, 0);
        acc[i + 4][j + 2] = __builtin_amdgcn_mfma_f32_16x16x32_bf16(a1[i][1], b1[j][1], acc[i + 4][j + 2], 0, 0, 0);
      }
    __builtin_amdgcn_s_setprio(0);
  }

  // ---------------------------- epilogue -----------------------------------
#pragma unroll
  for (int i = 0; i < 8; ++i) {
    const int rb = rowStart + wm + i * 16 + quad * 4;
#pragma unroll
    for (int j = 0; j < 4; ++j) {
      const int gc = colStart + wn + j * 16 + l16;
      const float bv = bias[gc];
#pragma unroll
      for (int r = 0; r < 4; ++r) {
        const int row = rb + r;
        float v = acc[i][j][r] + bv;
        if (GELU_EPI) {
          v = gelu_exact(v) * 32.0f;
          const int grow = row + (row >> 10) + 1;   // b*1024+p -> b*1025+p+1
          Cg[(size_t)grow * 1024 + gc] = f2bf(v);
        } else {
          if (row < Mvalid) {
            const int p = row % 1025;
            Cf[(size_t)row * 1024 + gc] = v + pos[(size_t)p * 1024 + gc];
          }
        }
      }
    }
  }
}

// --------------------------- launcher --------------------------------------

extern "C" void kernel_launch(void* const* d_in, const int* in_sizes, int n_in,
                              void* d_out, int out_size, void* d_ws, size_t ws_size,
                              hipStream_t stream) {
  const float* spikes  = (const float*)d_in[0];
  const float* W_embed = (const float*)d_in[1];
  const float* b_embed = (const float*)d_in[2];
  const float* cls     = (const float*)d_in[3];
  const float* W_proj  = (const float*)d_in[4];
  const float* b_proj  = (const float*)d_in[5];
  const float* pos     = (const float*)d_in[6];
  float* out = (float*)d_out;

  char* ws = (char*)d_ws;
  unsigned short* P  = (unsigned short*)(ws);              // 32 MiB
  unsigned short* G  = (unsigned short*)(ws + 33554432);   // 64.25 MiB
  unsigned short* WE = (unsigned short*)(ws + 100925440);  // 1 MiB
  unsigned short* WP = (unsigned short*)(ws + 101974016);  // 2 MiB

  hipLaunchKernelGGL(cast_f32_bf16, dim3(2048), dim3(256), 0, stream, W_embed, WE, 524288);
  hipLaunchKernelGGL(cast_f32_bf16, dim3(4096), dim3(256), 0, stream, W_proj, WP, 1048576);
  hipLaunchKernelGGL(patchify, dim3(16384), dim3(256), 0, stream, spikes, P);
  hipLaunchKernelGGL(g0_and_pad, dim3(384), dim3(256), 0, stream, cls, G);
  hipLaunchKernelGGL(mask_stamp, dim3(129), dim3(256), 0, stream, out);

  // GEMM1: [32768,512] x [1024,512]^T -> gelu*32 -> G (bf16). 128x4 = 512 blocks.
  hipLaunchKernelGGL((gemm_bt<512, true>), dim3(512), dim3(512), 0, stream,
                     P, WE, b_embed, G, (float*)nullptr, (const float*)nullptr,
                     0, 32767, 128);
  // GEMM2: [32896,1024] x [1024,1024]^T -> +b_proj +pos -> out (f32).
  // 129x4 = 516 blocks; last row-block clamps A reads to zeroed row 32895.
  hipLaunchKernelGGL((gemm_bt<1024, false>), dim3(516), dim3(512), 0, stream,
                     G, WP, b_proj, (unsigned short*)nullptr, out, pos,
                     32800, 32895, 129);
}

// Round 2
// 419.927 us; speedup vs baseline: 1.1229x; 1.1229x over previous
//
#include <hip/hip_runtime.h>
#include <stdint.h>

// ---------------------------------------------------------------------------
// NeuralEmbeddingLayer: patchify -> GEMM1(+bias,gelu,x32) -> GEMM2(+bias,+pos)
// R4 = R2 (verified 128x128/4-wave data path) + minimal T3 2-phase pipeline:
//  - LDS double-buffered (2 x 32KB = 64KB -> 2 blocks/CU)
//  - per K-tile: issue stage(t+1 -> buf^1) FIRST, then counted VMCNT(8)
//    (waits only tile t's loads, issued one iteration earlier), raw barrier,
//    compute tile t, barrier. Prefetch for t+1 stays in flight across the
//    whole compute of tile t (never drained to 0 mid-loop).
//  - all addressing/swizzle/epilogue formulas identical to R2.
// ---------------------------------------------------------------------------

typedef __attribute__((ext_vector_type(8))) short bf16x8;   // 8 bf16 = 4 VGPRs
typedef __attribute__((ext_vector_type(4))) float f32x4;    // MFMA C/D frag

#define VMCNT(n) asm volatile("s_waitcnt vmcnt(" #n ")" ::: "memory")
#define CFENCE() asm volatile("" ::: "memory")

__device__ __forceinline__ unsigned short f2bf(float f) {
  union { float f; unsigned u; } v; v.f = f;
  const unsigned u = v.u;
  return (unsigned short)((u + 0x7fffu + ((u >> 16) & 1u)) >> 16);  // RNE
}

__device__ __forceinline__ float gelu_exact(float x) {
  return 0.5f * x * (1.0f + erff(x * 0.70710678118654752440f));
}

// async global->LDS, 16B per lane. HW writes lds_base(lane0) + lane*16.
__device__ __forceinline__ void gl_lds16(const unsigned short* g, unsigned short* l) {
  __builtin_amdgcn_global_load_lds(
      (const __attribute__((address_space(1))) unsigned int*)g,
      (__attribute__((address_space(3))) unsigned int*)l, 16, 0, 0);
}

// --------------------------- prep kernels ----------------------------------

__global__ void cast_f32_bf16(const float* __restrict__ src,
                              unsigned short* __restrict__ dst, int n) {
  const int i = blockIdx.x * 256 + threadIdx.x;
  if (i < n) dst[i] = f2bf(src[i]);
}

// spikes [32][512][1024] f32 -> patches bf16 [32768][512]
__global__ void patchify(const float* __restrict__ spikes,
                         unsigned short* __restrict__ P) {
  const int idx = blockIdx.x * 256 + threadIdx.x;
  const int m = idx >> 7;
  const int c = (idx & 127) << 2;
  const int b = m >> 10, p = m & 1023;
  const int pt = p >> 5, ps = p & 31;
  const int ft = c >> 5, fs = c & 31;
  const float4 v = *(const float4*)(spikes +
      (size_t)(((b << 9) + pt * 16 + ft) << 10) + ps * 32 + fs);
  ushort4 o;
  o.x = f2bf(v.x); o.y = f2bf(v.y); o.z = f2bf(v.z); o.w = f2bf(v.w);
  *(ushort4*)(P + (size_t)m * 512 + c) = o;
}

// G rows b*1025 = gelu(cls)*32 (cls skips b_embed); zero pad rows [32800,32896)
__global__ void g0_and_pad(const float* __restrict__ cls,
                           unsigned short* __restrict__ G) {
  const int i = blockIdx.x * 256 + threadIdx.x;  // 98304 threads
  G[(size_t)32800 * 1024 + i] = 0;
  if (i < 1024) {
    const unsigned short bv = f2bf(gelu_exact(cls[i]) * 32.0f);
    for (int b = 0; b < 32; ++b) G[(size_t)(b * 1025) * 1024 + i] = bv;
  }
}

__global__ void mask_stamp(float* __restrict__ out) {
  const int i = blockIdx.x * 256 + threadIdx.x;
  if (i < 32800) {
    out[33587200 + i] = 1.0f;
    out[33587200 + 32800 + i] = (float)(i % 1025);
  }
}

// --------------------------- staging ---------------------------------------
// LDS granule (row,slot) holds global k-chunk slot^(row&7); elem offset g*8
// (lane-linear, as global_load_lds requires). 16KB per matrix per tile.
__device__ __forceinline__ void stage_tile(
    const unsigned short* __restrict__ A, const unsigned short* __restrict__ B,
    int K, int rowStart, int colStart, int k0, int g0,
    unsigned short* la, unsigned short* lb) {
#pragma unroll
  for (int s = 0; s < 4; ++s) {
    const int g = g0 + s * 64;
    const int r = g >> 3;
    const int slot = g & 7;
    const int kc = (slot ^ (r & 7)) << 3;
    gl_lds16(A + (size_t)(rowStart + r) * K + (k0 + kc), la + r * 64 + slot * 8);
    gl_lds16(B + (size_t)(colStart + r) * K + (k0 + kc), lb + r * 64 + slot * 8);
  }
}

// --------------------------- NT GEMM core ----------------------------------
// C[M,N] = A[M,K]*B[N,K]^T. 128x128 tile, BK=64, 4 waves x (4x4) 16x16x32 mfma.
// ROWBLKS: 256 (GEMM1) or 257 (GEMM2, extra row-block round-robined per XCD).
template <int K, bool GELU_EPI, int ROWBLKS>
__global__ __launch_bounds__(256) void gemm_bt(
    const unsigned short* __restrict__ A, const unsigned short* __restrict__ B,
    const float* __restrict__ bias, unsigned short* __restrict__ Cg,
    float* __restrict__ Cf, const float* __restrict__ pos, int Mvalid) {
  __shared__ __align__(16) unsigned short lsA[2][128 * 64];
  __shared__ __align__(16) unsigned short lsB[2][128 * 64];
  constexpr int NT = K / 64;

  const int tid = threadIdx.x;
  const int lane = tid & 63;
  const int w = tid >> 6;
  const int quad = lane >> 4;
  const int l16 = lane & 15;

  // XCD-locality swizzle (R2-verified). Each xcd owns rows [xcd*32, +32),
  // iterated row-major so 8 A-sharing col-blocks are concurrent on one XCD.
  const int L = blockIdx.x;
  const int xcd = L & 7;
  const int j = L >> 3;
  int rowBlk, colBlk;
  if (ROWBLKS > 256 && j >= 256) { rowBlk = 256; colBlk = xcd; }
  else { rowBlk = xcd * 32 + (j >> 3); colBlk = j & 7; }
  const int rowStart = rowBlk * 128;
  const int colStart = colBlk * 128;
  const int wm = (w >> 1) * 64;
  const int wn = (w & 1) * 64;

  f32x4 acc[4][4];
  const f32x4 z = {0.f, 0.f, 0.f, 0.f};
#pragma unroll
  for (int i = 0; i < 4; ++i)
#pragma unroll
    for (int j2 = 0; j2 < 4; ++j2) acc[i][j2] = z;

  const int g0 = w * 256 + lane;

  // prologue: tile 0 -> buffer 0 (8 loads in flight, no wait)
  stage_tile(A, B, K, rowStart, colStart, 0, g0, lsA[0], lsB[0]);

  for (int t = 0; t < NT; ++t) {
    const int cur = t & 1;
    if (t + 1 < NT) {
      // issue next tile's 8 loads EARLY, then wait only for tile t's 8
      // (issued one full iteration ago -> latency hidden under compute)
      stage_tile(A, B, K, rowStart, colStart, (t + 1) * 64, g0,
                 lsA[cur ^ 1], lsB[cur ^ 1]);
      VMCNT(8);
    } else {
      VMCNT(0);
    }
    __builtin_amdgcn_s_barrier();
    CFENCE();

    const unsigned short* cA = lsA[cur];
    const unsigned short* cB = lsB[cur];
#pragma unroll
    for (int kk = 0; kk < 64; kk += 32) {
      bf16x8 af[4], bfr[4];
      const int kcb = (kk >> 3) + quad;          // logical k-chunk 0..7
#pragma unroll
      for (int i = 0; i < 4; ++i) {
        const int r = wm + i * 16 + l16;
        af[i] = *(const bf16x8*)(cA + r * 64 + ((kcb ^ (r & 7)) << 3));
      }
#pragma unroll
      for (int j2 = 0; j2 < 4; ++j2) {
        const int r = wn + j2 * 16 + l16;
        bfr[j2] = *(const bf16x8*)(cB + r * 64 + ((kcb ^ (r & 7)) << 3));
      }
#pragma unroll
      for (int i = 0; i < 4; ++i)
#pragma unroll
        for (int j2 = 0; j2 < 4; ++j2)
          acc[i][j2] = __builtin_amdgcn_mfma_f32_16x16x32_bf16(af[i], bfr[j2],
                                                               acc[i][j2], 0, 0, 0);
    }

    CFENCE();
    __builtin_amdgcn_s_barrier();   // all reads of buf[cur] done before next
    CFENCE();                       // iteration's staging overwrites it
  }

  // ---------------------------- epilogue (R2 verbatim) ----------------------
#pragma unroll
  for (int i = 0; i < 4; ++i) {
    const int rb = rowStart + wm + i * 16 + quad * 4;
#pragma unroll
    for (int j2 = 0; j2 < 4; ++j2) {
      const int gc = colStart + wn + j2 * 16 + l16;
      const float bv = bias[gc];
#pragma unroll
      for (int r = 0; r < 4; ++r) {
        const int row = rb + r;
        float v = acc[i][j2][r] + bv;
        if (GELU_EPI) {
          v = gelu_exact(v) * 32.0f;
          const int grow = row + (row >> 10) + 1;   // b*1024+p -> b*1025+p+1
          Cg[(size_t)grow * 1024 + gc] = f2bf(v);
        } else {
          if (row < Mvalid) {
            const int p = row % 1025;               // magic-mul, cheap
            Cf[(size_t)row * 1024 + gc] = v + pos[(size_t)p * 1024 + gc];
          }
        }
      }
    }
  }
}

// --------------------------- launcher --------------------------------------

extern "C" void kernel_launch(void* const* d_in, const int* in_sizes, int n_in,
                              void* d_out, int out_size, void* d_ws, size_t ws_size,
                              hipStream_t stream) {
  const float* spikes  = (const float*)d_in[0];
  const float* W_embed = (const float*)d_in[1];
  const float* b_embed = (const float*)d_in[2];
  const float* cls     = (const float*)d_in[3];
  const float* W_proj  = (const float*)d_in[4];
  const float* b_proj  = (const float*)d_in[5];
  const float* pos     = (const float*)d_in[6];
  float* out = (float*)d_out;

  char* ws = (char*)d_ws;
  unsigned short* P  = (unsigned short*)(ws);              // 32 MiB
  unsigned short* G  = (unsigned short*)(ws + 33554432);   // 64.25 MiB
  unsigned short* WE = (unsigned short*)(ws + 100925440);  // 1 MiB
  unsigned short* WP = (unsigned short*)(ws + 101974016);  // 2 MiB

  hipLaunchKernelGGL(cast_f32_bf16, dim3(2048), dim3(256), 0, stream, W_embed, WE, 524288);
  hipLaunchKernelGGL(cast_f32_bf16, dim3(4096), dim3(256), 0, stream, W_proj, WP, 1048576);
  hipLaunchKernelGGL(patchify, dim3(16384), dim3(256), 0, stream, spikes, P);
  hipLaunchKernelGGL(g0_and_pad, dim3(384), dim3(256), 0, stream, cls, G);
  hipLaunchKernelGGL(mask_stamp, dim3(129), dim3(256), 0, stream, out);

  // GEMM1: [32768,512] x [1024,512]^T -> gelu*32 -> G (bf16), 2048 blocks
  hipLaunchKernelGGL((gemm_bt<512, true, 256>), dim3(2048), dim3(256), 0, stream,
                     P, WE, b_embed, G, (float*)nullptr, (const float*)nullptr, 0);
  // GEMM2: [32896,1024] x [1024,1024]^T -> +b_proj +pos -> out (f32), 2056 blocks
  hipLaunchKernelGGL((gemm_bt<1024, false, 257>), dim3(2056), dim3(256), 0, stream,
                     G, WP, b_proj, (unsigned short*)nullptr, out, pos, 32800);
}